// Round 16
// baseline (264.960 us; speedup 1.0000x reference)
//
#include <hip/hip_runtime.h>
#include <hip/hip_bf16.h>
#include <stdint.h>
#include <stddef.h>

typedef __attribute__((ext_vector_type(8))) short short8;
typedef __attribute__((ext_vector_type(4))) float f32x4;
typedef __attribute__((ext_vector_type(16))) float f32x16;

#define MFMA16(a, b, c) __builtin_amdgcn_mfma_f32_16x16x32_bf16((a), (b), (c), 0, 0, 0)
#define MFMA32(a, b, c) __builtin_amdgcn_mfma_f32_32x32x16_bf16((a), (b), (c), 0, 0, 0)

// Q pre-scale: HEAD_DIM^-0.5 * log2(e); flash uses raw v_exp_f32 (exp2)
#define QSCALE 0.1803368801111204f

#if __has_builtin(__builtin_amdgcn_exp2f)
#define EXP2(x) __builtin_amdgcn_exp2f(x)
#else
#define EXP2(x) __builtin_exp2f(x)
#endif

__device__ __forceinline__ float b2f(short x) {
    unsigned u = ((unsigned)(unsigned short)x) << 16;
    float f; __builtin_memcpy(&f, &u, 4); return f;
}
// round-nearest-even f32->bf16 (scalar)
__device__ __forceinline__ short f2b(float f) {
    unsigned u; __builtin_memcpy(&u, &f, 4);
    u = (u + 0x7FFFu + ((u >> 16) & 1u)) >> 16;
    return (short)u;
}
// two f32 -> packed bf16x2 in 3 VALU (2 adds + v_perm), round-half-up.
// (__float22bfloat162_rn is a multi-instr software sequence — r12 evidence.)
__device__ __forceinline__ unsigned pack2(float a, float b) {
    unsigned ua, ub; __builtin_memcpy(&ua, &a, 4); __builtin_memcpy(&ub, &b, 4);
    return __builtin_amdgcn_perm(ub + 0x8000u, ua + 0x8000u, 0x07060302u);
}
// 8 contiguous f32 -> bf16x8 (RNE)
__device__ __forceinline__ short8 load8f(const float* p) {
    const float4 f0 = *(const float4*)p;
    const float4 f1 = *(const float4*)(p + 4);
    short8 r;
    r[0]=f2b(f0.x); r[1]=f2b(f0.y); r[2]=f2b(f0.z); r[3]=f2b(f0.w);
    r[4]=f2b(f1.x); r[5]=f2b(f1.y); r[6]=f2b(f1.z); r[7]=f2b(f1.w);
    return r;
}

// ---------------------------------------------------------------------------
// Fused f32->bf16 converter for up to 3 arrays. nX = elems/8.
// ---------------------------------------------------------------------------
__global__ __launch_bounds__(256) void cvt3(
    const float* __restrict__ s0, short* __restrict__ d0, int n0,
    const float* __restrict__ s1, short* __restrict__ d1, int n1,
    const float* __restrict__ s2, short* __restrict__ d2, int n2)
{
    int i = blockIdx.x * 256 + threadIdx.x;
    if (i < n0) { *(short8*)(d0 + (size_t)i * 8) = load8f(s0 + (size_t)i * 8); return; }
    i -= n0;
    if (i < n1) { *(short8*)(d1 + (size_t)i * 8) = load8f(s1 + (size_t)i * 8); return; }
    i -= n1;
    if (i < n2) { *(short8*)(d2 + (size_t)i * 8) = load8f(s2 + (size_t)i * 8); }
}

// ---------------------------------------------------------------------------
// Fused QKV GEMM (bf16 in/out). Grid (64,12): sec = y>>2 (0=Q,1=K,2=V).
//   Q (x QSCALE) -> Qb[bh][seq][64];  K -> Kb[bh][seq][64]
//   V -> Vb[bh][64][seq] via LDS-transposed epilogue (coalesced b128 stores)
// ---------------------------------------------------------------------------
__global__ __launch_bounds__(256) void qkv_gemm(
    const short* __restrict__ X, const short* __restrict__ W,
    const float* __restrict__ bias,
    short* __restrict__ Qb, short* __restrict__ Kb, short* __restrict__ Vb)
{
    __shared__ short sT[128][132];

    const int tid  = threadIdx.x;
    const int wv   = tid >> 6;
    const int lane = tid & 63;
    const int l15  = lane & 15;
    const int quad = lane >> 4;
    const int m0   = blockIdx.x * 128 + (wv >> 1) * 64;
    const int sec  = blockIdx.y >> 2;
    const int bis  = blockIdx.y & 3;
    const int nbase = sec * 512 + bis * 128;
    const int j0   = (wv & 1) * 64;

    const f32x4 zero = {0.f, 0.f, 0.f, 0.f};
    f32x4 acc[4][4];
#pragma unroll
    for (int i = 0; i < 4; i++)
#pragma unroll
        for (int j = 0; j < 4; j++) acc[i][j] = zero;

    for (int k0 = 0; k0 < 512; k0 += 32) {
        short8 a[4], b[4];
#pragma unroll
        for (int i = 0; i < 4; i++)
            a[i] = *(const short8*)(X + (size_t)(m0 + i * 16 + l15) * 512 + k0 + quad * 8);
#pragma unroll
        for (int j = 0; j < 4; j++)
            b[j] = *(const short8*)(W + (size_t)(nbase + j0 + j * 16 + l15) * 512 + k0 + quad * 8);
#pragma unroll
        for (int i = 0; i < 4; i++)
#pragma unroll
            for (int j = 0; j < 4; j++)
                acc[i][j] = MFMA16(a[i], b[j], acc[i][j]);
    }

    if (sec < 2) {
        const float scale = (sec == 0) ? QSCALE : 1.0f;
        short* dst = (sec == 0) ? Qb : Kb;
#pragma unroll
        for (int j = 0; j < 4; j++) {
            const int jc = bis * 128 + j0 + j * 16 + l15;   // 0..511 in section
            const float bs = bias[sec * 512 + jc];
            const int hl = jc >> 6, d = jc & 63;
#pragma unroll
            for (int i = 0; i < 4; i++) {
#pragma unroll
                for (int r = 0; r < 4; r++) {
                    const int m = m0 + i * 16 + quad * 4 + r;
                    const int bb = m >> 12, seq = m & 4095;
                    dst[((size_t)(bb * 8 + hl) * 4096 + seq) * 64 + d] =
                        f2b((acc[i][j][r] + bs) * scale);
                }
            }
        }
    } else {
        // V: pack 4 consecutive seq into b64 LDS writes, then coalesced b128
#pragma unroll
        for (int j = 0; j < 4; j++) {
            const int jcl = j0 + j * 16 + l15;             // 0..127
            const float bs = bias[nbase + jcl];
#pragma unroll
            for (int i = 0; i < 4; i++) {
                uint2 w;
                w.x = pack2(acc[i][j][0] + bs, acc[i][j][1] + bs);
                w.y = pack2(acc[i][j][2] + bs, acc[i][j][3] + bs);
                *(uint2*)&sT[jcl][(wv >> 1) * 64 + i * 16 + quad * 4] = w;
            }
        }
        __syncthreads();

        const int jcl = tid >> 1, half = tid & 1;
        const int hl = (bis * 128 + jcl) >> 6;
        const int d  = jcl & 63;
        const int bb = (blockIdx.x * 128) >> 12;
        const int seq0 = ((blockIdx.x * 128) & 4095) + half * 64;
        short* dst = Vb + ((size_t)(bb * 8 + hl) * 64 + d) * 4096 + seq0;
#pragma unroll
        for (int u = 0; u < 8; u++)
            *(short8*)(dst + u * 8) = *(const short8*)&sT[jcl][half * 64 + u * 8];
    }
}

// ---------------------------------------------------------------------------
// Flash attention — 32x32x16 MFMA restructure. Flash is combined-issue-port
// bound (r13: VALU -24pts no gain; r14: DS reads -29% no gain), so the lever
// is total instruction count: one wave computes all 32 of its queries in ONE
// MFMA tile-set.
//   S^T (64key x 32q): 2 key-tiles x 4 d-steps = 8 MFMA32 (was 16 MFMA16)
//   PV  (64d x 32q):   2 d-tiles  x 4 k-steps = 8 MFMA32 (was 16 MFMA16)
//   + ONE sP phase + ONE fence per tile (was 2 phases + 3 fences)
// Layouts: C/D col=lane&31, row=(reg&3)+8*(reg>>2)+4*(lane>>5) [HW-verified
// m74/m101]; A[m=lane&31][k=(lane>>5)*8+j], B[k=(lane>>5)*8+j][n=lane&31]
// (generalization of the m89-verified 16x16 maps). Row sums back in VALU
// (32 adds + final shfl_xor(32)) to keep VGPR ~120 (no 16-reg lac).
// Grid (32,16,2), 4-wave blocks, LDS 36.9 KB (r13: LDS size doesn't move
// occupancy; r10 was fastest at this size).
// Split-K=2 partials (no-max streaming softmax): O = (l0*O0+l1*O1)/(l0+l1).
// ---------------------------------------------------------------------------
__global__ __launch_bounds__(256) void flash_attn(
    const short* __restrict__ Q, const short* __restrict__ K,
    const short* __restrict__ V, short* __restrict__ PO0,
    short* __restrict__ PO1, float* __restrict__ lbuf, int ktiles)
{
    __shared__ short sK[64][72];
    __shared__ short sV[64][72];          // sV[d][key]
    __shared__ short sP[4][32][72];       // [wave][query][key]

    const int tid  = threadIdx.x;
    const int wv   = tid >> 6;
    const int lane = tid & 63;
    const int l31  = lane & 31;
    const int half = lane >> 5;           // 0/1
    const int bh = blockIdx.y;
    const int b = bh >> 3, h = bh & 7;
    const int qw = blockIdx.x * 128 + wv * 32;   // wave's 32 queries
    const int ks = blockIdx.z;
    const int key0 = ks * ktiles * 64;

    const short* Qb = Q + (size_t)bh * 4096 * 64;
    const short* Kb = K + (size_t)bh * 4096 * 64;
    const short* Vb = V + (size_t)bh * 64 * 4096;

    // Q B-frags: B[k=d][n=query l31]; step s covers d = s*16 + half*8 + j
    short8 aq[4];
#pragma unroll
    for (int s = 0; s < 4; s++)
        aq[s] = *(const short8*)(Qb + (size_t)(qw + l31) * 64 + s * 16 + half * 8);

    f32x16 o0 = {}, o1 = {};              // O^T acc, d-tiles 0/1 (col=query)
    float lsum = 0.f;                     // this lane's half of query l31's sum

    // staging: 1024 16B-chunks (K:512, V:512) over 256 threads -> 2+2 each
    int srow[2], scb[2];
#pragma unroll
    for (int i = 0; i < 2; i++) {
        const int c = tid + i * 256;
        srow[i] = c >> 3; scb[i] = (c & 7) * 8;
    }
    short8 pk[2], pv[2];
#pragma unroll
    for (int i = 0; i < 2; i++) {
        pk[i] = *(const short8*)(Kb + (size_t)(key0 + srow[i]) * 64 + scb[i]);
        pv[i] = *(const short8*)(Vb + (size_t)srow[i] * 4096 + key0 + scb[i]);
    }

    for (int kt = 0; kt < ktiles; ++kt) {
        const int k0 = key0 + kt * 64;
        __syncthreads();               // all waves done reading prev tile
#pragma unroll
        for (int i = 0; i < 2; i++) {
            *(short8*)&sK[srow[i]][scb[i]] = pk[i];
            *(short8*)&sV[srow[i]][scb[i]] = pv[i];
        }
        __syncthreads();               // staging visible

        if (kt + 1 < ktiles) {         // prefetch next tile (overlaps compute)
            const int k0n = k0 + 64;
#pragma unroll
            for (int i = 0; i < 2; i++) {
                pk[i] = *(const short8*)(Kb + (size_t)(k0n + srow[i]) * 64 + scb[i]);
                pv[i] = *(const short8*)(Vb + (size_t)srow[i] * 4096 + k0n + scb[i]);
            }
        }

        // S^T per key-tile c: A=K[key][d] from LDS, B=Q. C: col=query,
        // row=key_local=(reg&3)+8*(reg>>2)+4*half -> reg-quad q holds 4
        // consecutive keys at c*32 + 8q + 4*half. exp + pack + sP store.
#pragma unroll
        for (int c = 0; c < 2; c++) {
            f32x16 ST = {};
#pragma unroll
            for (int s = 0; s < 4; s++) {
                const short8 bk = *(const short8*)&sK[c * 32 + l31][s * 16 + half * 8];
                ST = MFMA32(bk, aq[s], ST);
            }
#pragma unroll
            for (int q = 0; q < 4; q++) {
                const float p0 = EXP2(ST[4 * q + 0]), p1 = EXP2(ST[4 * q + 1]);
                const float p2 = EXP2(ST[4 * q + 2]), p3 = EXP2(ST[4 * q + 3]);
                lsum += (p0 + p1) + (p2 + p3);
                uint2 w; w.x = pack2(p0, p1); w.y = pack2(p2, p3);
                *(uint2*)&sP[wv][l31][c * 32 + q * 8 + half * 4] = w;
            }
        }
        __threadfence_block();         // wave-private sP: write -> read order

        // P^T B-frags: B[k=key][n=query] -> contiguous b128 at row l31
        short8 bp[4];
#pragma unroll
        for (int s = 0; s < 4; s++)
            bp[s] = *(const short8*)&sP[wv][l31][s * 16 + half * 8];

        // O^T += V^T x P^T : A=V^T[d][key] from LDS
#pragma unroll
        for (int s = 0; s < 4; s++) {
            const short8 bv0 = *(const short8*)&sV[l31][s * 16 + half * 8];
            const short8 bv1 = *(const short8*)&sV[32 + l31][s * 16 + half * 8];
            o0 = MFMA32(bv0, bp[s], o0);
            o1 = MFMA32(bv1, bp[s], o1);
        }
        __threadfence_block();         // sP reads done before next tile writes
    }

    // full row sum for query l31: this lane + its half-partner (lane^32)
    lsum += __shfl_xor(lsum, 32);
    const float inv = 1.f / fmaxf(lsum, 1e-30f);

    short* PO = (ks == 0) ? PO0 : PO1;
    // O^T: reg-quad q = 4 consecutive d at 8q + 4*half (+32 for o1), query l31
#pragma unroll
    for (int q = 0; q < 4; q++) {
        uint2 w0, w1;
        w0.x = pack2(o0[4 * q + 0] * inv, o0[4 * q + 1] * inv);
        w0.y = pack2(o0[4 * q + 2] * inv, o0[4 * q + 3] * inv);
        w1.x = pack2(o1[4 * q + 0] * inv, o1[4 * q + 1] * inv);
        w1.y = pack2(o1[4 * q + 2] * inv, o1[4 * q + 3] * inv);
        const size_t rowoff = ((size_t)b * 4096 + qw + l31) * 512;
        const int col = h * 64 + q * 8 + half * 4;
        *(uint2*)(PO + rowoff + col) = w0;
        *(uint2*)(PO + rowoff + col + 32) = w1;
    }
    if (half == 0)
        lbuf[((size_t)ks * 16 + bh) * 4096 + qw + l31] = lsum;
}

// ---------------------------------------------------------------------------
// Combine the 2 key-split partials: attn(ws) = (l0*O0 + l1*O1)/(l0+l1).
// Writes to ws (Qf region, dead after flash) so proj can write d_out
// directly with no hazard. Element-wise, memory-bound.
// ---------------------------------------------------------------------------
__global__ __launch_bounds__(256) void combine(
    const short* __restrict__ PO0, const short* __restrict__ PO1,
    short* __restrict__ attn, const float* __restrict__ L)
{
    const int i = blockIdx.x * 256 + threadIdx.x;   // 0..524287
    const size_t flat = (size_t)i * 8;
    const int col = (int)(flat & 511);
    const int q   = (int)((flat >> 9) & 4095);
    const int b   = (int)(flat >> 21);
    const int bh  = b * 8 + (col >> 6);
    const float l0 = L[(size_t)bh * 4096 + q];
    const float l1 = L[(size_t)65536 + (size_t)bh * 4096 + q];
    const float inv = 1.f / (l0 + l1);
    const float w0 = l0 * inv, w1 = l1 * inv;
    const short8 a = *(const short8*)(PO0 + flat);
    const short8 c = *(const short8*)(PO1 + flat);
    short8 r;
#pragma unroll
    for (int k = 0; k < 8; k += 2) {
        const unsigned p = pack2(w0 * b2f(a[k]) + w1 * b2f(c[k]),
                                 w0 * b2f(a[k + 1]) + w1 * b2f(c[k + 1]));
        r[k]     = (short)(p & 0xFFFF);
        r[k + 1] = (short)(p >> 16);
    }
    *(short8*)(attn + flat) = r;
}

// ---------------------------------------------------------------------------
// Projection, single full-GPU launch: grid (64,4) = 256 blocks.
// dst = d_out f32 direct (A from ws-attn: no read/write hazard).
// ---------------------------------------------------------------------------
__global__ __launch_bounds__(256) void proj_gemm(
    const short* __restrict__ A, const short* __restrict__ W,
    const float* __restrict__ bias, float* __restrict__ dst)
{
    const int tid  = threadIdx.x;
    const int wv   = tid >> 6;
    const int lane = tid & 63;
    const int l15  = lane & 15;
    const int quad = lane >> 4;
    const int m0 = blockIdx.x * 128 + (wv >> 1) * 64;   // 0..8191
    const int n0 = blockIdx.y * 128 + (wv & 1) * 64;

    const f32x4 zero = {0.f, 0.f, 0.f, 0.f};
    f32x4 acc[4][4];
#pragma unroll
    for (int i = 0; i < 4; i++)
#pragma unroll
        for (int j = 0; j < 4; j++) acc[i][j] = zero;

    for (int k0 = 0; k0 < 512; k0 += 32) {
        short8 a[4], b[4];
#pragma unroll
        for (int i = 0; i < 4; i++)
            a[i] = *(const short8*)(A + (size_t)(m0 + i * 16 + l15) * 512 + k0 + quad * 8);
#pragma unroll
        for (int j = 0; j < 4; j++)
            b[j] = *(const short8*)(W + (size_t)(n0 + j * 16 + l15) * 512 + k0 + quad * 8);
#pragma unroll
        for (int i = 0; i < 4; i++)
#pragma unroll
            for (int j = 0; j < 4; j++)
                acc[i][j] = MFMA16(a[i], b[j], acc[i][j]);
    }

#pragma unroll
    for (int j = 0; j < 4; j++) {
        const int n = n0 + j * 16 + l15;
        const float bs = bias[n];
#pragma unroll
        for (int i = 0; i < 4; i++) {
#pragma unroll
            for (int r = 0; r < 4; r++) {
                const int m = m0 + i * 16 + quad * 4 + r;
                dst[(size_t)m * 512 + n] = acc[i][j][r] + bs;
            }
        }
    }
}

// ---------------------------------------------------------------------------
// Memory plan (ws >= 25 MB, proven). 5 dispatches:
//   d_out [0,8M):    xb -> PO0 (flash split 0) -> proj output [0,8M)
//   d_out [8M,9.5M): wb (dead after qkv)
//   d_out [8M,16M):  PO1 (flash split 1) -> proj output [8M,16M)
//   ws [0,8M):  Qf -> attn (combine output; Qf dead after flash)
//   ws [8M,16M) Kf | [16M,24M) Vf | [24M,24.5M) lbuf | [24.5M,25M) pwb
// ---------------------------------------------------------------------------
extern "C" void kernel_launch(void* const* d_in, const int* in_sizes, int n_in,
                              void* d_out, int out_size, void* d_ws, size_t ws_size,
                              hipStream_t stream)
{
    const float* x      = (const float*)d_in[0];   // [2,4096,512] f32
    const float* qkv_w  = (const float*)d_in[1];   // [1536,512]   f32
    const float* qkv_b  = (const float*)d_in[2];   // [1536]       f32
    const float* proj_w = (const float*)d_in[3];   // [512,512]    f32
    const float* proj_b = (const float*)d_in[4];   // [512]        f32

    const size_t MB = 1024 * 1024;
    short* xb   = (short*)d_out;
    short* wb   = (short*)d_out + 4 * MB;
    short* PO0  = (short*)d_out;                   // [0,8M) after xb dies
    short* PO1  = (short*)d_out + 4 * MB;          // [8M,16M) after wb dies
    float* out  = (float*)d_out;

    short* Qf = (short*)d_ws;
    short* Kf = Qf + (size_t)16 * 4096 * 64;
    short* Vf = Kf + (size_t)16 * 4096 * 64;       // [bh][64][4096]
    short* attn = Qf;                              // ws [0,8M), post-flash life
    float* lbuf = (float*)((char*)d_ws + 24 * MB);
    short* pwb  = (short*)((char*)d_ws + 24 * MB + 512 * 1024);

    cvt3<<<2560, 256, 0, stream>>>(x, xb, 524288, qkv_w, wb, 98304, proj_w, pwb, 32768);
    qkv_gemm<<<dim3(64, 12), 256, 0, stream>>>(xb, wb, qkv_b, Qf, Kf, Vf);
    flash_attn<<<dim3(32, 16, 2), 256, 0, stream>>>(Qf, Kf, Vf, PO0, PO1, lbuf, 32);
    combine<<<2048, 256, 0, stream>>>(PO0, PO1, attn, lbuf);
    proj_gemm<<<dim3(64, 4), 256, 0, stream>>>(attn, pwb, proj_b, out);
}

// Round 18
// 250.038 us; speedup vs baseline: 1.0597x; 1.0597x over previous
//
#include <hip/hip_runtime.h>
#include <hip/hip_bf16.h>
#include <stdint.h>
#include <stddef.h>

typedef __attribute__((ext_vector_type(8))) short short8;
typedef __attribute__((ext_vector_type(4))) float f32x4;
typedef __attribute__((ext_vector_type(16))) float f32x16;

#define MFMA16(a, b, c) __builtin_amdgcn_mfma_f32_16x16x32_bf16((a), (b), (c), 0, 0, 0)
#define MFMA32(a, b, c) __builtin_amdgcn_mfma_f32_32x32x16_bf16((a), (b), (c), 0, 0, 0)

// Q pre-scale: HEAD_DIM^-0.5 * log2(e); flash uses raw v_exp_f32 (exp2)
#define QSCALE 0.1803368801111204f

#if __has_builtin(__builtin_amdgcn_exp2f)
#define EXP2(x) __builtin_amdgcn_exp2f(x)
#else
#define EXP2(x) __builtin_exp2f(x)
#endif

__device__ __forceinline__ float b2f(short x) {
    unsigned u = ((unsigned)(unsigned short)x) << 16;
    float f; __builtin_memcpy(&f, &u, 4); return f;
}
// round-nearest-even f32->bf16 (scalar)
__device__ __forceinline__ short f2b(float f) {
    unsigned u; __builtin_memcpy(&u, &f, 4);
    u = (u + 0x7FFFu + ((u >> 16) & 1u)) >> 16;
    return (short)u;
}
// two f32 -> packed bf16x2 in 3 VALU (2 adds + v_perm), round-half-up.
// (__float22bfloat162_rn is a multi-instr software sequence — r12 evidence.)
__device__ __forceinline__ unsigned pack2(float a, float b) {
    unsigned ua, ub; __builtin_memcpy(&ua, &a, 4); __builtin_memcpy(&ub, &b, 4);
    return __builtin_amdgcn_perm(ub + 0x8000u, ua + 0x8000u, 0x07060302u);
}
// 8 contiguous f32 -> bf16x8 (RNE)
__device__ __forceinline__ short8 load8f(const float* p) {
    const float4 f0 = *(const float4*)p;
    const float4 f1 = *(const float4*)(p + 4);
    short8 r;
    r[0]=f2b(f0.x); r[1]=f2b(f0.y); r[2]=f2b(f0.z); r[3]=f2b(f0.w);
    r[4]=f2b(f1.x); r[5]=f2b(f1.y); r[6]=f2b(f1.z); r[7]=f2b(f1.w);
    return r;
}

// ---------------------------------------------------------------------------
// Fused f32->bf16 converter for up to 3 arrays. nX = elems/8.
// ---------------------------------------------------------------------------
__global__ __launch_bounds__(256) void cvt3(
    const float* __restrict__ s0, short* __restrict__ d0, int n0,
    const float* __restrict__ s1, short* __restrict__ d1, int n1,
    const float* __restrict__ s2, short* __restrict__ d2, int n2)
{
    int i = blockIdx.x * 256 + threadIdx.x;
    if (i < n0) { *(short8*)(d0 + (size_t)i * 8) = load8f(s0 + (size_t)i * 8); return; }
    i -= n0;
    if (i < n1) { *(short8*)(d1 + (size_t)i * 8) = load8f(s1 + (size_t)i * 8); return; }
    i -= n1;
    if (i < n2) { *(short8*)(d2 + (size_t)i * 8) = load8f(s2 + (size_t)i * 8); }
}

// ---------------------------------------------------------------------------
// Fused QKV GEMM (bf16 in/out). Grid (64,12): sec = y>>2 (0=Q,1=K,2=V).
//   Q (x QSCALE) -> Qb[bh][seq][64];  K -> Kb[bh][seq][64]
//   V -> Vb[bh][64][seq] via LDS-transposed epilogue (coalesced b128 stores)
// ---------------------------------------------------------------------------
__global__ __launch_bounds__(256) void qkv_gemm(
    const short* __restrict__ X, const short* __restrict__ W,
    const float* __restrict__ bias,
    short* __restrict__ Qb, short* __restrict__ Kb, short* __restrict__ Vb)
{
    __shared__ short sT[128][132];

    const int tid  = threadIdx.x;
    const int wv   = tid >> 6;
    const int lane = tid & 63;
    const int l15  = lane & 15;
    const int quad = lane >> 4;
    const int m0   = blockIdx.x * 128 + (wv >> 1) * 64;
    const int sec  = blockIdx.y >> 2;
    const int bis  = blockIdx.y & 3;
    const int nbase = sec * 512 + bis * 128;
    const int j0   = (wv & 1) * 64;

    const f32x4 zero = {0.f, 0.f, 0.f, 0.f};
    f32x4 acc[4][4];
#pragma unroll
    for (int i = 0; i < 4; i++)
#pragma unroll
        for (int j = 0; j < 4; j++) acc[i][j] = zero;

    for (int k0 = 0; k0 < 512; k0 += 32) {
        short8 a[4], b[4];
#pragma unroll
        for (int i = 0; i < 4; i++)
            a[i] = *(const short8*)(X + (size_t)(m0 + i * 16 + l15) * 512 + k0 + quad * 8);
#pragma unroll
        for (int j = 0; j < 4; j++)
            b[j] = *(const short8*)(W + (size_t)(nbase + j0 + j * 16 + l15) * 512 + k0 + quad * 8);
#pragma unroll
        for (int i = 0; i < 4; i++)
#pragma unroll
            for (int j = 0; j < 4; j++)
                acc[i][j] = MFMA16(a[i], b[j], acc[i][j]);
    }

    if (sec < 2) {
        const float scale = (sec == 0) ? QSCALE : 1.0f;
        short* dst = (sec == 0) ? Qb : Kb;
#pragma unroll
        for (int j = 0; j < 4; j++) {
            const int jc = bis * 128 + j0 + j * 16 + l15;   // 0..511 in section
            const float bs = bias[sec * 512 + jc];
            const int hl = jc >> 6, d = jc & 63;
#pragma unroll
            for (int i = 0; i < 4; i++) {
#pragma unroll
                for (int r = 0; r < 4; r++) {
                    const int m = m0 + i * 16 + quad * 4 + r;
                    const int bb = m >> 12, seq = m & 4095;
                    dst[((size_t)(bb * 8 + hl) * 4096 + seq) * 64 + d] =
                        f2b((acc[i][j][r] + bs) * scale);
                }
            }
        }
    } else {
        // V: pack 4 consecutive seq into b64 LDS writes, then coalesced b128
#pragma unroll
        for (int j = 0; j < 4; j++) {
            const int jcl = j0 + j * 16 + l15;             // 0..127
            const float bs = bias[nbase + jcl];
#pragma unroll
            for (int i = 0; i < 4; i++) {
                uint2 w;
                w.x = pack2(acc[i][j][0] + bs, acc[i][j][1] + bs);
                w.y = pack2(acc[i][j][2] + bs, acc[i][j][3] + bs);
                *(uint2*)&sT[jcl][(wv >> 1) * 64 + i * 16 + quad * 4] = w;
            }
        }
        __syncthreads();

        const int jcl = tid >> 1, half = tid & 1;
        const int hl = (bis * 128 + jcl) >> 6;
        const int d  = jcl & 63;
        const int bb = (blockIdx.x * 128) >> 12;
        const int seq0 = ((blockIdx.x * 128) & 4095) + half * 64;
        short* dst = Vb + ((size_t)(bb * 8 + hl) * 64 + d) * 4096 + seq0;
#pragma unroll
        for (int u = 0; u < 8; u++)
            *(short8*)(dst + u * 8) = *(const short8*)&sT[jcl][half * 64 + u * 8];
    }
}

// ---------------------------------------------------------------------------
// Flash attention — r16's MFMA32 compute, now with 8-WAVE BLOCKS (512 thr,
// 256 queries/block), grid (16,16,2) = 512 blocks = exactly 2/CU, all
// co-resident (LDS 55.3 KB x 2 <= 160 KB) -> 16 waves/CU.
// Rationale: flash has been ~115us across 6 variants (VALU -24pts, DS -29%,
// conflicts -71%, MFMA instrs -55% all neutral). Untested axis: work per
// staging barrier. 8-wave blocks halve per-CU staging traffic, K/V global
// fetch, and barrier count while keeping 32 q/wave (r11's regression was
// 6-wave/CU TLP starvation; this DOUBLES waves/CU instead).
// Layouts as r16 (HW-verified): C/D col=lane&31, row=(reg&3)+8*(reg>>2)+
// 4*(lane>>5); A[m=lane&31][k=(lane>>5)*8+j]. Ones-free VALU row sums.
// Split-K=2 partials (no-max streaming softmax): O = (l0*O0+l1*O1)/(l0+l1).
// ---------------------------------------------------------------------------
__global__ __launch_bounds__(512) void flash_attn(
    const short* __restrict__ Q, const short* __restrict__ K,
    const short* __restrict__ V, short* __restrict__ PO0,
    short* __restrict__ PO1, float* __restrict__ lbuf, int ktiles)
{
    __shared__ short sK[64][72];
    __shared__ short sV[64][72];          // sV[d][key]
    __shared__ short sP[8][32][72];       // [wave][query][key]

    const int tid  = threadIdx.x;
    const int wv   = tid >> 6;            // 0..7
    const int lane = tid & 63;
    const int l31  = lane & 31;
    const int half = lane >> 5;           // 0/1
    const int bh = blockIdx.y;
    const int b = bh >> 3, h = bh & 7;
    const int qw = blockIdx.x * 256 + wv * 32;   // wave's 32 queries
    const int ks = blockIdx.z;
    const int key0 = ks * ktiles * 64;

    const short* Qb = Q + (size_t)bh * 4096 * 64;
    const short* Kb = K + (size_t)bh * 4096 * 64;
    const short* Vb = V + (size_t)bh * 64 * 4096;

    // Q B-frags: B[k=d][n=query l31]; step s covers d = s*16 + half*8 + j
    short8 aq[4];
#pragma unroll
    for (int s = 0; s < 4; s++)
        aq[s] = *(const short8*)(Qb + (size_t)(qw + l31) * 64 + s * 16 + half * 8);

    f32x16 o0 = {}, o1 = {};              // O^T acc, d-tiles 0/1 (col=query)
    float lsum = 0.f;

    // staging: 512 K-chunks + 512 V-chunks over 512 threads -> 1+1 each
    const int srow = tid >> 3, scb = (tid & 7) * 8;
    short8 pk, pv;
    pk = *(const short8*)(Kb + (size_t)(key0 + srow) * 64 + scb);
    pv = *(const short8*)(Vb + (size_t)srow * 4096 + key0 + scb);

    for (int kt = 0; kt < ktiles; ++kt) {
        const int k0 = key0 + kt * 64;
        __syncthreads();               // all waves done reading prev tile
        *(short8*)&sK[srow][scb] = pk;
        *(short8*)&sV[srow][scb] = pv;
        __syncthreads();               // staging visible

        if (kt + 1 < ktiles) {         // prefetch next tile (overlaps compute)
            const int k0n = k0 + 64;
            pk = *(const short8*)(Kb + (size_t)(k0n + srow) * 64 + scb);
            pv = *(const short8*)(Vb + (size_t)srow * 4096 + k0n + scb);
        }

        // S^T per key-tile c: A=K[key][d] from LDS, B=Q. reg-quad q holds
        // 4 consecutive keys at c*32 + 8q + 4*half. exp + pack + sP store.
#pragma unroll
        for (int c = 0; c < 2; c++) {
            f32x16 ST = {};
#pragma unroll
            for (int s = 0; s < 4; s++) {
                const short8 bk = *(const short8*)&sK[c * 32 + l31][s * 16 + half * 8];
                ST = MFMA32(bk, aq[s], ST);
            }
#pragma unroll
            for (int q = 0; q < 4; q++) {
                const float p0 = EXP2(ST[4 * q + 0]), p1 = EXP2(ST[4 * q + 1]);
                const float p2 = EXP2(ST[4 * q + 2]), p3 = EXP2(ST[4 * q + 3]);
                lsum += (p0 + p1) + (p2 + p3);
                uint2 w; w.x = pack2(p0, p1); w.y = pack2(p2, p3);
                *(uint2*)&sP[wv][l31][c * 32 + q * 8 + half * 4] = w;
            }
        }
        __threadfence_block();         // wave-private sP: write -> read order

        // P^T B-frags: contiguous b128 at row l31
        short8 bp[4];
#pragma unroll
        for (int s = 0; s < 4; s++)
            bp[s] = *(const short8*)&sP[wv][l31][s * 16 + half * 8];

        // O^T += V^T x P^T : A=V^T[d][key] from LDS
#pragma unroll
        for (int s = 0; s < 4; s++) {
            const short8 bv0 = *(const short8*)&sV[l31][s * 16 + half * 8];
            const short8 bv1 = *(const short8*)&sV[32 + l31][s * 16 + half * 8];
            o0 = MFMA32(bv0, bp[s], o0);
            o1 = MFMA32(bv1, bp[s], o1);
        }
        __threadfence_block();         // sP reads done before next tile writes
    }

    // full row sum for query l31: this lane + its half-partner (lane^32)
    lsum += __shfl_xor(lsum, 32);
    const float inv = 1.f / fmaxf(lsum, 1e-30f);

    short* PO = (ks == 0) ? PO0 : PO1;
    // O^T: reg-quad q = 4 consecutive d at 8q + 4*half (+32 for o1), query l31
#pragma unroll
    for (int q = 0; q < 4; q++) {
        uint2 w0, w1;
        w0.x = pack2(o0[4 * q + 0] * inv, o0[4 * q + 1] * inv);
        w0.y = pack2(o0[4 * q + 2] * inv, o0[4 * q + 3] * inv);
        w1.x = pack2(o1[4 * q + 0] * inv, o1[4 * q + 1] * inv);
        w1.y = pack2(o1[4 * q + 2] * inv, o1[4 * q + 3] * inv);
        const size_t rowoff = ((size_t)b * 4096 + qw + l31) * 512;
        const int col = h * 64 + q * 8 + half * 4;
        *(uint2*)(PO + rowoff + col) = w0;
        *(uint2*)(PO + rowoff + col + 32) = w1;
    }
    if (half == 0)
        lbuf[((size_t)ks * 16 + bh) * 4096 + qw + l31] = lsum;
}

// ---------------------------------------------------------------------------
// Combine the 2 key-split partials: attn(ws) = (l0*O0 + l1*O1)/(l0+l1).
// Writes to ws (Qf region, dead after flash) so proj can write d_out
// directly with no hazard. Element-wise, memory-bound.
// ---------------------------------------------------------------------------
__global__ __launch_bounds__(256) void combine(
    const short* __restrict__ PO0, const short* __restrict__ PO1,
    short* __restrict__ attn, const float* __restrict__ L)
{
    const int i = blockIdx.x * 256 + threadIdx.x;   // 0..524287
    const size_t flat = (size_t)i * 8;
    const int col = (int)(flat & 511);
    const int q   = (int)((flat >> 9) & 4095);
    const int b   = (int)(flat >> 21);
    const int bh  = b * 8 + (col >> 6);
    const float l0 = L[(size_t)bh * 4096 + q];
    const float l1 = L[(size_t)65536 + (size_t)bh * 4096 + q];
    const float inv = 1.f / (l0 + l1);
    const float w0 = l0 * inv, w1 = l1 * inv;
    const short8 a = *(const short8*)(PO0 + flat);
    const short8 c = *(const short8*)(PO1 + flat);
    short8 r;
#pragma unroll
    for (int k = 0; k < 8; k += 2) {
        const unsigned p = pack2(w0 * b2f(a[k]) + w1 * b2f(c[k]),
                                 w0 * b2f(a[k + 1]) + w1 * b2f(c[k + 1]));
        r[k]     = (short)(p & 0xFFFF);
        r[k + 1] = (short)(p >> 16);
    }
    *(short8*)(attn + flat) = r;
}

// ---------------------------------------------------------------------------
// Projection, single full-GPU launch: grid (64,4) = 256 blocks.
// dst = d_out f32 direct (A from ws-attn: no read/write hazard).
// ---------------------------------------------------------------------------
__global__ __launch_bounds__(256) void proj_gemm(
    const short* __restrict__ A, const short* __restrict__ W,
    const float* __restrict__ bias, float* __restrict__ dst)
{
    const int tid  = threadIdx.x;
    const int wv   = tid >> 6;
    const int lane = tid & 63;
    const int l15  = lane & 15;
    const int quad = lane >> 4;
    const int m0 = blockIdx.x * 128 + (wv >> 1) * 64;   // 0..8191
    const int n0 = blockIdx.y * 128 + (wv & 1) * 64;

    const f32x4 zero = {0.f, 0.f, 0.f, 0.f};
    f32x4 acc[4][4];
#pragma unroll
    for (int i = 0; i < 4; i++)
#pragma unroll
        for (int j = 0; j < 4; j++) acc[i][j] = zero;

    for (int k0 = 0; k0 < 512; k0 += 32) {
        short8 a[4], b[4];
#pragma unroll
        for (int i = 0; i < 4; i++)
            a[i] = *(const short8*)(A + (size_t)(m0 + i * 16 + l15) * 512 + k0 + quad * 8);
#pragma unroll
        for (int j = 0; j < 4; j++)
            b[j] = *(const short8*)(W + (size_t)(n0 + j * 16 + l15) * 512 + k0 + quad * 8);
#pragma unroll
        for (int i = 0; i < 4; i++)
#pragma unroll
            for (int j = 0; j < 4; j++)
                acc[i][j] = MFMA16(a[i], b[j], acc[i][j]);
    }

#pragma unroll
    for (int j = 0; j < 4; j++) {
        const int n = n0 + j * 16 + l15;
        const float bs = bias[n];
#pragma unroll
        for (int i = 0; i < 4; i++) {
#pragma unroll
            for (int r = 0; r < 4; r++) {
                const int m = m0 + i * 16 + quad * 4 + r;
                dst[(size_t)m * 512 + n] = acc[i][j][r] + bs;
            }
        }
    }
}

// ---------------------------------------------------------------------------
// Memory plan (ws >= 25 MB, proven). 5 dispatches (r16 structure — the
// cooperative single-dispatch fusion failed to launch in this harness, r17):
//   d_out [0,8M):    xb -> PO0 (flash split 0) -> proj output [0,8M)
//   d_out [8M,9.5M): wb (dead after qkv)
//   d_out [8M,16M):  PO1 (flash split 1) -> proj output [8M,16M)
//   ws [0,8M):  Qf -> attn (combine output; Qf dead after flash)
//   ws [8M,16M) Kf | [16M,24M) Vf | [24M,24.5M) lbuf | [24.5M,25M) pwb
// ---------------------------------------------------------------------------
extern "C" void kernel_launch(void* const* d_in, const int* in_sizes, int n_in,
                              void* d_out, int out_size, void* d_ws, size_t ws_size,
                              hipStream_t stream)
{
    const float* x      = (const float*)d_in[0];   // [2,4096,512] f32
    const float* qkv_w  = (const float*)d_in[1];   // [1536,512]   f32
    const float* qkv_b  = (const float*)d_in[2];   // [1536]       f32
    const float* proj_w = (const float*)d_in[3];   // [512,512]    f32
    const float* proj_b = (const float*)d_in[4];   // [512]        f32

    const size_t MB = 1024 * 1024;
    short* xb   = (short*)d_out;
    short* wb   = (short*)d_out + 4 * MB;
    short* PO0  = (short*)d_out;                   // [0,8M) after xb dies
    short* PO1  = (short*)d_out + 4 * MB;          // [8M,16M) after wb dies
    float* out  = (float*)d_out;

    short* Qf = (short*)d_ws;
    short* Kf = Qf + (size_t)16 * 4096 * 64;
    short* Vf = Kf + (size_t)16 * 4096 * 64;       // [bh][64][4096]
    short* attn = Qf;                              // ws [0,8M), post-flash life
    float* lbuf = (float*)((char*)d_ws + 24 * MB);
    short* pwb  = (short*)((char*)d_ws + 24 * MB + 512 * 1024);

    cvt3<<<2560, 256, 0, stream>>>(x, xb, 524288, qkv_w, wb, 98304, proj_w, pwb, 32768);
    qkv_gemm<<<dim3(64, 12), 256, 0, stream>>>(xb, wb, qkv_b, Qf, Kf, Vf);
    flash_attn<<<dim3(16, 16, 2), 512, 0, stream>>>(Qf, Kf, Vf, PO0, PO1, lbuf, 32);
    combine<<<2048, 256, 0, stream>>>(PO0, PO1, attn, lbuf);
    proj_gemm<<<dim3(64, 4), 256, 0, stream>>>(attn, pwb, proj_b, out);
}